// Round 1
// baseline (784.701 us; speedup 1.0000x reference)
//
#include <hip/hip_runtime.h>

// out[b,i,n,o] = sum_{l,j,k} W[l,j,k,i] * valid(o,k) *
//   ( maskA(n,j)*x[b,l,n+j-1,wk] + maskB(n,j)*x[b,128+l,(n+6)%7+j-1,wk] )
// wk = (o+k+5)%7 ; valid(o,k): not(o==0&&k==0) and not(o==6&&k==2)

#define IOUT 512

__global__ __launch_bounds__(256) void fused_shift_conv_f32(
    const float* __restrict__ x, const float* __restrict__ Wt,
    float* __restrict__ out)
{
    // y[l,n,j,w] layout: l*147 + n*21 + j*7 + w   (128*7*3*7 = 18816 floats)
    __shared__ float ys[128 * 147];

    const int b = blockIdx.x;
    const int t = threadIdx.x;
    const float* xb = x + (size_t)b * (256 * 49);

    // ---- phase 1: build combined tensor y into LDS ----
    for (int e = t; e < 128 * 147; e += 256) {
        int w = e % 7;
        int j = (e / 7) % 3;
        int n = (e / 21) % 7;
        int l = e / 147;
        int rA = n + j - 1;
        int rB = ((n + 6) % 7) + j - 1;
        float v = 0.f;
        if (rA >= 0 && rA < 7) v += xb[(l * 7 + rA) * 7 + w];
        if (rB >= 0 && rB < 7) v += xb[((128 + l) * 7 + rB) * 7 + w];
        ys[e] = v;
    }
    __syncthreads();

    // ---- phase 2: each thread owns output channels i0=t, i1=t+256 ----
    float acc[2][49];
#pragma unroll
    for (int ii = 0; ii < 2; ++ii)
#pragma unroll
        for (int m = 0; m < 49; ++m) acc[ii][m] = 0.f;

    const int i0 = t;
    const int i1 = t + 256;

    for (int lj = 0; lj < 384; ++lj) {
        const int l = lj / 3;
        const int j = lj - l * 3;
        const float* wp = Wt + (size_t)(l * 9 + j * 3) * IOUT;
        float wv0[3], wv1[3];
#pragma unroll
        for (int k = 0; k < 3; ++k) {
            wv0[k] = wp[k * IOUT + i0];
            wv1[k] = wp[k * IOUT + i1];
        }
        const float* yb = &ys[l * 147 + j * 7];
#pragma unroll
        for (int n = 0; n < 7; ++n) {
            float yr[7];
#pragma unroll
            for (int w = 0; w < 7; ++w) yr[w] = yb[n * 21 + w];
#pragma unroll
            for (int k = 0; k < 3; ++k) {
#pragma unroll
                for (int o = 0; o < 7; ++o) {
                    if ((k == 0 && o == 0) || (k == 2 && o == 6)) continue;
                    const int wk = (o + k + 5) % 7;
                    acc[0][n * 7 + o] = fmaf(wv0[k], yr[wk], acc[0][n * 7 + o]);
                    acc[1][n * 7 + o] = fmaf(wv1[k], yr[wk], acc[1][n * 7 + o]);
                }
            }
        }
    }

    // ---- epilogue ----
    float* ob = out + (size_t)b * (IOUT * 49);
    {
        float* op = ob + (size_t)i0 * 49;
#pragma unroll
        for (int m = 0; m < 49; ++m) op[m] = acc[0][m];
    }
    {
        float* op = ob + (size_t)i1 * 49;
#pragma unroll
        for (int m = 0; m < 49; ++m) op[m] = acc[1][m];
    }
}

extern "C" void kernel_launch(void* const* d_in, const int* in_sizes, int n_in,
                              void* d_out, int out_size, void* d_ws, size_t ws_size,
                              hipStream_t stream) {
    const float* x  = (const float*)d_in[0];  // (1024, 256, 7, 7)
    const float* Wt = (const float*)d_in[1];  // (128, 3, 3, 512)
    float* out = (float*)d_out;               // (1024, 512, 7, 7)
    (void)in_sizes; (void)n_in; (void)out_size; (void)d_ws; (void)ws_size;

    dim3 grid(1024);
    dim3 block(256);
    hipLaunchKernelGGL(fused_shift_conv_f32, grid, block, 0, stream, x, Wt, out);
}

// Round 2
// 289.842 us; speedup vs baseline: 2.7073x; 2.7073x over previous
//
#include <hip/hip_runtime.h>

typedef __attribute__((ext_vector_type(8))) __bf16 bvec8;
typedef __attribute__((ext_vector_type(4))) float fvec4;
typedef __attribute__((ext_vector_type(8))) short svec8;

#define NKT 36  // K = 1152 = 36 tiles of 32 ; K' = (j*3+k)*128 + l

__device__ __forceinline__ void gload16(const void* g, void* l) {
    __builtin_amdgcn_global_load_lds(
        (const __attribute__((address_space(1))) void*)g,
        (__attribute__((address_space(3))) void*)l,
        16, 0, 0);
}

__device__ __forceinline__ bvec8 bzero8() {
    svec8 z = (svec8)0;
    return __builtin_bit_cast(bvec8, z);
}

// ---- pack W[l][j][k][i] fp32 -> Wp bf16, frag-ready ----
// unit u = (ktg*32 + itg)*64 + lane ; Wp[u*8+e] = W[Kp][i]
//   Kp = ktg*32 + (lane>>4)*8 + e ; i = itg*16 + (lane&15)
__global__ __launch_bounds__(256) void pack_w(const float* __restrict__ W,
                                              __bf16* __restrict__ Wp) {
    int u = blockIdx.x * 256 + threadIdx.x;
    if (u >= NKT * 32 * 64) return;  // 73728 units
    int lane = u & 63;
    int itg  = (u >> 6) & 31;
    int ktg  = u >> 11;
    int i = (itg << 4) + (lane & 15);
    int Kp0 = ktg * 32 + ((lane >> 4) << 3);
    bvec8 o;
#pragma unroll
    for (int e = 0; e < 8; ++e) {
        int Kp = Kp0 + e;
        int jk = Kp >> 7;      // 0..8
        int l  = Kp & 127;
        int j  = jk / 3, k = jk - j * 3;
        o[e] = (__bf16)W[((l * 9 + j * 3 + k) << 9) + i];
    }
    *(bvec8*)&Wp[(size_t)u * 8] = o;
}

// ---- main: C[s, i] = sum_K A[s,K] * W[K,i] per batch ----
__global__ __launch_bounds__(256) void conv_mfma(
    const float* __restrict__ x, const __bf16* __restrict__ Wp,
    float* __restrict__ out)
{
    __shared__ __bf16 ys[147 * 136];   // [ (n*3+j)*7+w ][ l(128)+pad8 ]
    __shared__ __bf16 wbuf[2][4096];   // dbuf 128i x 32K frag-ready

    const int b    = blockIdx.x;
    const int ib   = blockIdx.y;       // i-block of 128
    const int t    = threadIdx.x;
    const int wv   = t >> 6;
    const int lane = t & 63;
    const int li   = lane & 15;
    const int ks   = lane >> 4;

    const float* xb = x + (size_t)b * (256 * 49);

    // stage kt=0 W tile early (completion covered by barrier below)
    {
        const char* g = ((const char*)Wp) + (size_t)(ib * 8) * 1024 + wv * 1024 + lane * 16;
        char* l = ((char*)&wbuf[0][0]) + wv * 1024;
        gload16(g, l);
        gload16(g + 4096, l + 4096);
    }

    // zero-init the two A-less (n,j) slots: (0,0) and (6,2)
    if (t < 224) {
        int pair = t / 112;            // 0:(n=0,j=0) 1:(n=6,j=2)
        int w    = (t / 16) % 7;
        int seg  = t & 15;
        int njw  = pair ? (6 * 3 + 2) * 7 + w : w;
        *(svec8*)&ys[njw * 136 + seg * 8] = (svec8)0;
    }

    // phase A: channels c in [0,128): ys[(r+1-j,j,w,l)] = x[b,l,r,w]
    for (int it = 0; it < 25; ++it) {
        int e = it * 256 + t;
        if (e < 6272) {
            float v = xb[e];           // fully coalesced
            int w = e % 7;
            int r = (e / 7) % 7;
            int l = e / 49;
#pragma unroll
            for (int j = 0; j < 3; ++j) {
                int n = r + 1 - j;
                if (n >= 0 && n < 7)
                    ys[((n * 3 + j) * 7 + w) * 136 + l] = (__bf16)v;
            }
        }
    }
    __syncthreads();
    // phase B: channels c in [128,256): ys[((r-j+2)%7,j,w,l)] += x[b,128+l,r,w]
    for (int it = 0; it < 25; ++it) {
        int e = it * 256 + t;
        if (e < 6272) {
            float v = xb[6272 + e];
            int w = e % 7;
            int r = (e / 7) % 7;
            int l = e / 49;
#pragma unroll
            for (int j = 0; j < 3; ++j) {
                int q = r - j + 1;
                if (q >= 0 && q < 7) {
                    int n = q + 1; if (n >= 7) n -= 7;
                    int idx = ((n * 3 + j) * 7 + w) * 136 + l;
                    ys[idx] = (__bf16)((float)ys[idx] + v);
                }
            }
        }
    }

    // per-m-tile row geometry (row s = mt*16 + li)
    int nn[4], oo[4]; bool sv[4];
#pragma unroll
    for (int mt = 0; mt < 4; ++mt) {
        int s = mt * 16 + li;
        sv[mt] = (s < 49);
        int sc = sv[mt] ? s : 0;
        nn[mt] = sc / 7;
        oo[mt] = sc % 7;
    }

    fvec4 acc[4][2];
#pragma unroll
    for (int mt = 0; mt < 4; ++mt)
#pragma unroll
        for (int ii = 0; ii < 2; ++ii)
            acc[mt][ii] = (fvec4){0.f, 0.f, 0.f, 0.f};

    __syncthreads();  // ys complete + wbuf[0] staged (full vmcnt drain)

#pragma unroll
    for (int jk = 0; jk < 9; ++jk) {
        const int j = jk / 3, k = jk - (jk / 3) * 3;
        int base[4]; bool msk[4];
#pragma unroll
        for (int mt = 0; mt < 4; ++mt) {
            int tw = oo[mt] + k + 5;
            int w = tw >= 7 ? tw - 7 : tw;                  // (o+k+5)%7
            msk[mt] = sv[mt] && !((k == 0 && oo[mt] == 0) || (k == 2 && oo[mt] == 6));
            base[mt] = msk[mt] ? (((nn[mt] * 3 + j) * 7 + w) * 136 + ks * 8) : 0;
        }
#pragma unroll
        for (int lt = 0; lt < 4; ++lt) {
            const int kt = jk * 4 + lt;
            const int cur = kt & 1;
            if (kt + 1 < NKT) {  // stage next W tile into other buffer
                const char* g = ((const char*)Wp)
                    + (size_t)((kt + 1) * 32 + ib * 8) * 1024 + wv * 1024 + lane * 16;
                char* l = ((char*)&wbuf[cur ^ 1][0]) + wv * 1024;
                gload16(g, l);
                gload16(g + 4096, l + 4096);
            }
            bvec8 af[4];
#pragma unroll
            for (int mt = 0; mt < 4; ++mt) {
                bvec8 v = *(const bvec8*)&ys[base[mt] + lt * 32];
                af[mt] = msk[mt] ? v : bzero8();
            }
            bvec8 bf[2];
#pragma unroll
            for (int ii = 0; ii < 2; ++ii)
                bf[ii] = *(const bvec8*)&wbuf[cur][((wv * 2 + ii) * 64 + lane) * 8];
#pragma unroll
            for (int mt = 0; mt < 4; ++mt)
#pragma unroll
                for (int ii = 0; ii < 2; ++ii)
                    acc[mt][ii] = __builtin_amdgcn_mfma_f32_16x16x32_bf16(
                        af[mt], bf[ii], acc[mt][ii], 0, 0, 0);
            __syncthreads();
        }
    }

    // epilogue: out[b][i][s] ; D: col(lane&15)=i, row = mt*16 + ks*4 + r = s
    float* ob = out + ((size_t)b * 512 + (size_t)(ib * 128 + wv * 32)) * 49;
#pragma unroll
    for (int mt = 0; mt < 4; ++mt)
#pragma unroll
        for (int r = 0; r < 4; ++r) {
            int s = mt * 16 + ks * 4 + r;
            if (s < 49) {
#pragma unroll
                for (int ii = 0; ii < 2; ++ii)
                    ob[(size_t)(ii * 16 + li) * 49 + s] = acc[mt][ii][r];
            }
        }
}

extern "C" void kernel_launch(void* const* d_in, const int* in_sizes, int n_in,
                              void* d_out, int out_size, void* d_ws, size_t ws_size,
                              hipStream_t stream) {
    const float* x = (const float*)d_in[0];   // (1024,256,7,7)
    const float* W = (const float*)d_in[1];   // (128,3,3,512)
    float* out = (float*)d_out;               // (1024,512,7,7)
    __bf16* Wp = (__bf16*)d_ws;               // 1152*512 bf16 = 1.18 MB
    (void)in_sizes; (void)n_in; (void)out_size; (void)ws_size;

    hipLaunchKernelGGL(pack_w, dim3((NKT * 32 * 64 + 255) / 256), dim3(256), 0, stream, W, Wp);
    hipLaunchKernelGGL(conv_mfma, dim3(1024, 4), dim3(256), 0, stream, x, Wp, out);
}

// Round 3
// 141.891 us; speedup vs baseline: 5.5303x; 2.0427x over previous
//
#include <hip/hip_runtime.h>

typedef __attribute__((ext_vector_type(8))) __bf16 bvec8;
typedef __attribute__((ext_vector_type(4))) float fvec4;
typedef __attribute__((ext_vector_type(8))) short svec8;

#define NKT 36  // K = 1152 = 36 tiles of 32 ; K' = (j*3+k)*128 + l

__device__ __forceinline__ void gload16(const void* g, void* l) {
    __builtin_amdgcn_global_load_lds(
        (const __attribute__((address_space(1))) void*)g,
        (__attribute__((address_space(3))) void*)l,
        16, 0, 0);
}

__device__ __forceinline__ bvec8 bzero8() {
    svec8 z = (svec8)0;
    return __builtin_bit_cast(bvec8, z);
}

// ---- pack W[l][j][k][i] fp32 -> Wp bf16, frag-ready ----
// unit u = (ktg*32 + itg)*64 + lane ; Wp[u*8+e] = W[Kp][i]
//   Kp = ktg*32 + (lane>>4)*8 + e ; i = itg*16 + (lane&15)
__global__ __launch_bounds__(256) void pack_w(const float* __restrict__ W,
                                              __bf16* __restrict__ Wp) {
    int u = blockIdx.x * 256 + threadIdx.x;
    if (u >= NKT * 32 * 64) return;  // 73728 units
    int lane = u & 63;
    int itg  = (u >> 6) & 31;
    int ktg  = u >> 11;
    int i = (itg << 4) + (lane & 15);
    int Kp0 = ktg * 32 + ((lane >> 4) << 3);
    bvec8 o;
#pragma unroll
    for (int e = 0; e < 8; ++e) {
        int Kp = Kp0 + e;
        int jk = Kp >> 7;      // 0..8
        int l  = Kp & 127;
        int j  = jk / 3, k = jk - j * 3;
        o[e] = (__bf16)W[((l * 9 + j * 3 + k) << 9) + i];
    }
    *(bvec8*)&Wp[(size_t)u * 8] = o;
}

// ---- main: block = 2 batches x 512 i ; 512 threads = (wm 2) x (wi 4) waves
// ys[bb][row=(n*3+j)*7+w][l]  row stride 256B, 16B-unit swizzle u^=(row&15)
__global__ __launch_bounds__(512, 2) void conv_mfma(
    const float* __restrict__ x, const __bf16* __restrict__ Wp,
    float* __restrict__ out)
{
    extern __shared__ char smem[];
    __bf16* ys   = (__bf16*)smem;                 // 2*147*128 bf16 = 75264 B
    __bf16* wbuf = (__bf16*)(smem + 75264);       // 2 * 32768 B dbuf

    const int t    = threadIdx.x;
    const int wid  = t >> 6;
    const int lane = t & 63;
    const int li   = lane & 15;
    const int ks   = lane >> 4;
    const int wm   = wid >> 2;     // batch within block / m-half
    const int wi   = wid & 3;      // i-quarter (128 i each)
    const int b0   = blockIdx.x * 2;

    const float* xb = x + (size_t)b0 * (256 * 49);
    const char* WpB = (const char*)Wp;
    char* wbufB = (char*)wbuf;

    // stage kt=0 W tile (32 KB): linear both sides
#pragma unroll
    for (int r = 0; r < 4; ++r)
        gload16(WpB + (size_t)(t + 512 * r) * 16, wbufB + (t + 512 * r) * 16);

    // zero-init the A-less rows: (n=0,j=0,w) and (n=6,j=2,w), both batches
    if (t < 448) {
        int seg  = t & 15;
        int w    = (t >> 4) % 7;
        int kind = ((t >> 4) / 7) & 1;
        int bb   = t / 224;
        int njw  = kind ? (6 * 3 + 2) * 7 + w : w;
        *(svec8*)&ys[bb * 18816 + njw * 128 + seg * 8] = (svec8)0;
    }

    // phase A: channels [0,128): ys[bb][(r+1-j,j,w)][l] = x[b0+bb,l,r,w]
    for (int it = 0; it < 13; ++it) {
        int e = it * 512 + t;
        if (e < 6272) {
            int w = e % 7;
            int r = (e / 7) % 7;
            int l = e / 49;
#pragma unroll
            for (int bb = 0; bb < 2; ++bb) {
                float v = xb[bb * 12544 + e];
#pragma unroll
                for (int j = 0; j < 3; ++j) {
                    int n = r + 1 - j;
                    if (n >= 0 && n < 7) {
                        int row = (n * 3 + j) * 7 + w;
                        int idx = bb * 18816 + row * 128 +
                                  (((l >> 3) ^ (row & 15)) << 3) + (l & 7);
                        ys[idx] = (__bf16)v;
                    }
                }
            }
        }
    }
    __syncthreads();
    // phase B: channels [128,256): ys[bb][((r-j+2)%7,j,w)][l] += x[...]
    for (int it = 0; it < 13; ++it) {
        int e = it * 512 + t;
        if (e < 6272) {
            int w = e % 7;
            int r = (e / 7) % 7;
            int l = e / 49;
#pragma unroll
            for (int bb = 0; bb < 2; ++bb) {
                float v = xb[bb * 12544 + 6272 + e];
#pragma unroll
                for (int j = 0; j < 3; ++j) {
                    int q = r - j + 1;
                    if (q >= 0 && q < 7) {
                        int n = q + 1; if (n >= 7) n -= 7;
                        int row = (n * 3 + j) * 7 + w;
                        int idx = bb * 18816 + row * 128 +
                                  (((l >> 3) ^ (row & 15)) << 3) + (l & 7);
                        ys[idx] = (__bf16)((float)ys[idx] + v);
                    }
                }
            }
        }
    }

    // per-m-tile geometry: wave wm handles batch b0+wm, rows s = am*16 + li
    int nn[4], oo[4]; bool sv[4];
#pragma unroll
    for (int am = 0; am < 4; ++am) {
        int s = am * 16 + li;
        sv[am] = (s < 49);
        int sc = sv[am] ? s : 0;
        nn[am] = sc / 7;
        oo[am] = sc % 7;
    }

    fvec4 acc[4][8];
#pragma unroll
    for (int am = 0; am < 4; ++am)
#pragma unroll
        for (int ii = 0; ii < 8; ++ii)
            acc[am][ii] = (fvec4){0.f, 0.f, 0.f, 0.f};

    __syncthreads();  // ys complete + wbuf[0] landed (vmcnt drained)

    const int ysW = wm * 18816;            // wave's batch half (bf16 elems)

    for (int jk = 0; jk < 9; ++jk) {
        const int j = jk / 3, k = jk - (jk / 3) * 3;
        int rowE[4], rx[4]; bool msk[4];
#pragma unroll
        for (int am = 0; am < 4; ++am) {
            int tw = oo[am] + k + 5;
            int w = tw >= 7 ? tw - 7 : tw;               // (o+k+5)%7
            msk[am] = sv[am] && !((k == 0 && oo[am] == 0) || (k == 2 && oo[am] == 6));
            int row = msk[am] ? ((nn[am] * 3 + j) * 7 + w) : 0;
            rowE[am] = ysW + row * 128;
            rx[am]   = row & 15;
        }
#pragma unroll
        for (int lt = 0; lt < 4; ++lt) {
            const int kt  = jk * 4 + lt;
            const int cur = lt & 1;
            if (kt + 1 < NKT) {   // stage next tile into other buffer (issue early)
                const char* g = WpB + (size_t)(kt + 1) * 32768;
                char* d = wbufB + (cur ^ 1) * 32768;
#pragma unroll
                for (int r = 0; r < 4; ++r)
                    gload16(g + (t + 512 * r) * 16, d + (t + 512 * r) * 16);
            }
            bvec8 af[4];
#pragma unroll
            for (int am = 0; am < 4; ++am) {
                int u = (lt * 4 + ks) ^ rx[am];
                bvec8 v = *(const bvec8*)&ys[rowE[am] + u * 8];
                af[am] = msk[am] ? v : bzero8();
            }
            bvec8 bf[8];
#pragma unroll
            for (int ii = 0; ii < 8; ++ii)
                bf[ii] = *(const bvec8*)&wbuf[cur * 16384 + ((wi * 8 + ii) * 64 + lane) * 8];
#pragma unroll
            for (int am = 0; am < 4; ++am)
#pragma unroll
                for (int ii = 0; ii < 8; ++ii)
                    acc[am][ii] = __builtin_amdgcn_mfma_f32_16x16x32_bf16(
                        af[am], bf[ii], acc[am][ii], 0, 0, 0);
            __syncthreads();
        }
    }

    // epilogue: out[b0+wm][i][s] ; D: col=li -> i, row = ks*4+r -> s within tile
    float* ob = out + ((size_t)(b0 + wm) * 512) * 49;
#pragma unroll
    for (int am = 0; am < 4; ++am) {
#pragma unroll
        for (int ii = 0; ii < 8; ++ii) {
            int i = wi * 128 + ii * 16 + li;
            float* op = ob + (size_t)i * 49;
            if (am < 3) {
                int s0 = am * 16 + ks * 4;
#pragma unroll
                for (int r = 0; r < 4; ++r) op[s0 + r] = acc[am][ii][r];
            } else if (ks == 0) {
                op[48] = acc[3][ii][0];
            }
        }
    }
}

extern "C" void kernel_launch(void* const* d_in, const int* in_sizes, int n_in,
                              void* d_out, int out_size, void* d_ws, size_t ws_size,
                              hipStream_t stream) {
    const float* x = (const float*)d_in[0];   // (1024,256,7,7)
    const float* W = (const float*)d_in[1];   // (128,3,3,512)
    float* out = (float*)d_out;               // (1024,512,7,7)
    __bf16* Wp = (__bf16*)d_ws;               // 1152*512 bf16 = 1.18 MB
    (void)in_sizes; (void)n_in; (void)out_size; (void)ws_size;

    static bool attr_set = false;
    if (!attr_set) {
        hipFuncSetAttribute(reinterpret_cast<const void*>(conv_mfma),
                            hipFuncAttributeMaxDynamicSharedMemorySize, 140800);
        attr_set = true;
    }

    hipLaunchKernelGGL(pack_w, dim3((NKT * 32 * 64 + 255) / 256), dim3(256), 0, stream, W, Wp);
    hipLaunchKernelGGL(conv_mfma, dim3(512), dim3(512), 140800, stream, x, Wp, out);
}